// Round 1
// baseline (1518.575 us; speedup 1.0000x reference)
//
#include <hip/hip_runtime.h>
#include <cstdint>
#include <cstddef>

#define GN   16384
#define GIN  128
#define GOUT 64
#define LOG2E 1.44269504088896340736f

typedef __attribute__((ext_vector_type(8))) short short8;
typedef __attribute__((ext_vector_type(4))) float f32x4;

__device__ __forceinline__ unsigned short f2bf(float f) {
  unsigned u = __float_as_uint(f);
  u += 0x7FFFu + ((u >> 16) & 1u);          // round-to-nearest-even
  return (unsigned short)(u >> 16);
}

// ---------------------------------------------------------------------------
// prep: Wh = x@W (fp32 in regs), f_src/f_dst (pre-scaled by log2e),
//       WhB^T bf16 [64][N] for MFMA B-operand contiguity.
// One block = 64 rows, 256 threads: thread (r = t&63, s = t>>6) computes
// Wh[row][s*16 .. s*16+16).
// ---------------------------------------------------------------------------
__global__ __launch_bounds__(256) void prep_kernel(
    const float* __restrict__ x, const float* __restrict__ w,
    const float* __restrict__ aw, unsigned short* __restrict__ whbt,
    float* __restrict__ fs2, float* __restrict__ fd2)
{
  __shared__ float ws[GIN * GOUT];          // 32 KB
  __shared__ float red[2][64][4];

  const int t = threadIdx.x;
  const int rb = blockIdx.x * 64;

  for (int i = t; i < (GIN * GOUT) / 4; i += 256)
    ((float4*)ws)[i] = ((const float4*)w)[i];
  __syncthreads();

  const int r = t & 63, s = t >> 6;
  const int row = rb + r;
  const float* xr = x + (size_t)row * GIN;

  float acc[16];
#pragma unroll
  for (int d = 0; d < 16; ++d) acc[d] = 0.f;

  for (int kk = 0; kk < GIN; kk += 4) {
    float4 xv = *(const float4*)(xr + kk);
    float xa[4] = {xv.x, xv.y, xv.z, xv.w};
#pragma unroll
    for (int u = 0; u < 4; ++u) {
#pragma unroll
      for (int d = 0; d < 16; ++d)
        acc[d] += xa[u] * ws[(kk + u) * GOUT + s * 16 + d];
    }
  }

  float psrc = 0.f, pdst = 0.f;
#pragma unroll
  for (int d = 0; d < 16; ++d) {
    const int dg = s * 16 + d;
    psrc += acc[d] * aw[dg];
    pdst += acc[d] * aw[GOUT + dg];
    whbt[(size_t)dg * GN + row] = f2bf(acc[d]);
  }
  red[0][r][s] = psrc;
  red[1][r][s] = pdst;
  __syncthreads();
  if (s == 0) {
    float a_ = red[0][r][0] + red[0][r][1] + red[0][r][2] + red[0][r][3];
    float b_ = red[1][r][0] + red[1][r][1] + red[1][r][2] + red[1][r][3];
    fs2[row] = a_ * LOG2E;
    fd2[row] = b_ * LOG2E;
  }
}

// ---------------------------------------------------------------------------
// main: one wave per (strip of 16 rows, 1/8 chunk of columns).
// p built directly in MFMA A-fragment layout; no LDS, no barriers.
// ---------------------------------------------------------------------------
__global__ __launch_bounds__(256) void gat_main(
    const int* __restrict__ adj, const unsigned short* __restrict__ whbt,
    const float* __restrict__ fs2, const float* __restrict__ fd2,
    float* __restrict__ num, float* __restrict__ den)
{
  const int wave  = blockIdx.x * 4 + (threadIdx.x >> 6);
  const int lane  = threadIdx.x & 63;
  const int strip = wave & 1023;            // 1024 strips of 16 rows
  const int chunk = wave >> 10;             // 8 column chunks
  const int m = lane & 15;
  const int q = lane >> 4;
  const int row = strip * 16 + m;

  const float fsrow = fs2[row];
  const int CW = GN / 8;                    // 2048 columns per chunk
  const int j0 = chunk * CW;

  const int4*   __restrict__ arow = (const int4*)(adj + (size_t)row * GN);
  const float4* __restrict__ fdv  = (const float4*)fd2;

  f32x4 acc0 = {0.f, 0.f, 0.f, 0.f};
  f32x4 acc1 = {0.f, 0.f, 0.f, 0.f};
  f32x4 acc2 = {0.f, 0.f, 0.f, 0.f};
  f32x4 acc3 = {0.f, 0.f, 0.f, 0.f};
  float dsum = 0.f;

  auto pcalc = [&](int a, float fd) -> float {
    float sv = fsrow + fd;
    float lv = fmaxf(sv, 0.02f * sv);       // lrelu (commutes with *log2e)
    float pe = __builtin_amdgcn_exp2f(lv);
    pe = (a != 0) ? pe : 0.f;
    dsum += pe;
    return pe;
  };

  auto kstep = [&](int4 aA, int4 aB, float4 fA, float4 fB, int koff) {
    short8 af;
    af[0] = (short)f2bf(pcalc(aA.x, fA.x));
    af[1] = (short)f2bf(pcalc(aA.y, fA.y));
    af[2] = (short)f2bf(pcalc(aA.z, fA.z));
    af[3] = (short)f2bf(pcalc(aA.w, fA.w));
    af[4] = (short)f2bf(pcalc(aB.x, fB.x));
    af[5] = (short)f2bf(pcalc(aB.y, fB.y));
    af[6] = (short)f2bf(pcalc(aB.z, fB.z));
    af[7] = (short)f2bf(pcalc(aB.w, fB.w));

    const unsigned short* wb = whbt + koff + q * 8;
    short8 b0 = *(const short8*)(wb + (size_t)(0  + m) * GN);
    short8 b1 = *(const short8*)(wb + (size_t)(16 + m) * GN);
    short8 b2 = *(const short8*)(wb + (size_t)(32 + m) * GN);
    short8 b3 = *(const short8*)(wb + (size_t)(48 + m) * GN);

    acc0 = __builtin_amdgcn_mfma_f32_16x16x32_bf16(af, b0, acc0, 0, 0, 0);
    acc1 = __builtin_amdgcn_mfma_f32_16x16x32_bf16(af, b1, acc1, 0, 0, 0);
    acc2 = __builtin_amdgcn_mfma_f32_16x16x32_bf16(af, b2, acc2, 0, 0, 0);
    acc3 = __builtin_amdgcn_mfma_f32_16x16x32_bf16(af, b3, acc3, 0, 0, 0);
  };

#pragma unroll 2
  for (int j = j0; j < j0 + CW; j += 64) {
    const int i4 = (j >> 2) + (q << 1);
    int4 a0 = arow[i4];
    int4 a1 = arow[i4 + 1];
    int4 a2 = arow[i4 + 8];
    int4 a3 = arow[i4 + 9];
    float4 f0 = fdv[i4];
    float4 f1 = fdv[i4 + 1];
    float4 f2 = fdv[i4 + 8];
    float4 f3 = fdv[i4 + 9];

    kstep(a0, a1, f0, f1, j);
    kstep(a2, a3, f2, f3, j + 32);
  }

  // den: lanes m, m+16, m+32, m+48 hold partial sums of row m
  dsum += __shfl_xor(dsum, 16);
  dsum += __shfl_xor(dsum, 32);
  if (q == 0) unsafeAtomicAdd(&den[row], dsum);

  // C/D layout: D[row = q*4 + r][col = lane&15]
  const int orow0 = strip * 16 + q * 4;
#pragma unroll
  for (int r = 0; r < 4; ++r) {
    float* nr = num + (size_t)(orow0 + r) * GOUT + m;
    unsafeAtomicAdd(nr + 0,  acc0[r]);
    unsafeAtomicAdd(nr + 16, acc1[r]);
    unsafeAtomicAdd(nr + 32, acc2[r]);
    unsafeAtomicAdd(nr + 48, acc3[r]);
  }
}

// ---------------------------------------------------------------------------
// finalize: out = elu(num / den)
// ---------------------------------------------------------------------------
__global__ __launch_bounds__(256) void fin_kernel(
    const float* __restrict__ num, const float* __restrict__ den,
    float* __restrict__ out)
{
  const int g = blockIdx.x * 256 + threadIdx.x;
  if (g < GN * GOUT) {
    float v = num[g] / den[g >> 6];
    out[g] = (v > 0.f) ? v : expm1f(v);
  }
}

extern "C" void kernel_launch(void* const* d_in, const int* in_sizes, int n_in,
                              void* d_out, int out_size, void* d_ws, size_t ws_size,
                              hipStream_t stream) {
  const float* x   = (const float*)d_in[0];
  const int*   adj = (const int*)d_in[1];
  const float* w   = (const float*)d_in[2];
  const float* aw  = (const float*)d_in[3];
  float* out = (float*)d_out;

  // workspace layout (floats): num[N*64] | den[N] | fs2[N] | fd2[N] | whbt(bf16 64*N)
  float* num = (float*)d_ws;
  float* den = num + (size_t)GN * GOUT;
  float* fs2 = den + GN;
  float* fd2 = fs2 + GN;
  unsigned short* whbt = (unsigned short*)(fd2 + GN);
  // total ~6.5 MB

  hipMemsetAsync(num, 0, ((size_t)GN * GOUT + GN) * sizeof(float), stream);
  prep_kernel<<<GN / 64, 256, 0, stream>>>(x, w, aw, whbt, fs2, fd2);
  gat_main<<<(GN / 16) * 8 / 4, 256, 0, stream>>>(adj, whbt, fs2, fd2, num, den);
  fin_kernel<<<(GN * GOUT) / 256, 256, 0, stream>>>(num, den, out);
}

// Round 2
// 1482.734 us; speedup vs baseline: 1.0242x; 1.0242x over previous
//
#include <hip/hip_runtime.h>
#include <cstdint>
#include <cstddef>

#define GN   16384
#define GIN  128
#define GOUT 64
#define LOG2E 1.44269504088896340736f

typedef __attribute__((ext_vector_type(8))) short short8;
typedef __attribute__((ext_vector_type(4))) float f32x4;
typedef __attribute__((ext_vector_type(4))) int   int4v;

__device__ __forceinline__ unsigned short f2bf(float f) {
  unsigned u = __float_as_uint(f);
  u += 0x7FFFu + ((u >> 16) & 1u);          // round-to-nearest-even
  return (unsigned short)(u >> 16);
}

// ---------------------------------------------------------------------------
// prep: Wh = x@W (fp32 in regs), f_src/f_dst (pre-scaled by log2e),
//       WhB^T bf16 [64][N] for MFMA B-operand contiguity.
// ---------------------------------------------------------------------------
__global__ __launch_bounds__(256) void prep_kernel(
    const float* __restrict__ x, const float* __restrict__ w,
    const float* __restrict__ aw, unsigned short* __restrict__ whbt,
    float* __restrict__ fs2, float* __restrict__ fd2)
{
  __shared__ float ws[GIN * GOUT];          // 32 KB
  __shared__ float red[2][64][4];

  const int t = threadIdx.x;
  const int rb = blockIdx.x * 64;

  for (int i = t; i < (GIN * GOUT) / 4; i += 256)
    ((float4*)ws)[i] = ((const float4*)w)[i];
  __syncthreads();

  const int r = t & 63, s = t >> 6;
  const int row = rb + r;
  const float* xr = x + (size_t)row * GIN;

  float acc[16];
#pragma unroll
  for (int d = 0; d < 16; ++d) acc[d] = 0.f;

  for (int kk = 0; kk < GIN; kk += 4) {
    float4 xv = *(const float4*)(xr + kk);
    float xa[4] = {xv.x, xv.y, xv.z, xv.w};
#pragma unroll
    for (int u = 0; u < 4; ++u) {
#pragma unroll
      for (int d = 0; d < 16; ++d)
        acc[d] += xa[u] * ws[(kk + u) * GOUT + s * 16 + d];
    }
  }

  float psrc = 0.f, pdst = 0.f;
#pragma unroll
  for (int d = 0; d < 16; ++d) {
    const int dg = s * 16 + d;
    psrc += acc[d] * aw[dg];
    pdst += acc[d] * aw[GOUT + dg];
    whbt[(size_t)dg * GN + row] = f2bf(acc[d]);
  }
  red[0][r][s] = psrc;
  red[1][r][s] = pdst;
  __syncthreads();
  if (s == 0) {
    float a_ = red[0][r][0] + red[0][r][1] + red[0][r][2] + red[0][r][3];
    float b_ = red[1][r][0] + red[1][r][1] + red[1][r][2] + red[1][r][3];
    fs2[row] = a_ * LOG2E;
    fd2[row] = b_ * LOG2E;
  }
}

// ---------------------------------------------------------------------------
// main v2: one wave per (32 rows = 2 strips, 1/8 column chunk).
// B-fragments (whbt) are loaded ONCE per wave per K-step and shared by the
// two A-fragments -> halves whbt L1/L2 traffic vs v1. adj loads are
// nontemporal (no reuse; keep whbt/fd L2-resident). No LDS, no barriers.
// ---------------------------------------------------------------------------
__global__ __launch_bounds__(256) void gat_main(
    const int* __restrict__ adj, const unsigned short* __restrict__ whbt,
    const float* __restrict__ fs2, const float* __restrict__ fd2,
    float* __restrict__ num, float* __restrict__ den)
{
  const int wave  = blockIdx.x * 4 + (threadIdx.x >> 6);
  const int lane  = threadIdx.x & 63;
  const int strip = wave & 511;             // 512 strips of 32 rows
  const int chunk = wave >> 9;              // 8 column chunks
  const int m = lane & 15;
  const int q = lane >> 4;
  const int row0 = strip * 32 + m;
  const int row1 = row0 + 16;

  const float fs0 = fs2[row0];
  const float fs1 = fs2[row1];
  const int CW = GN / 8;                    // 2048 columns per chunk
  const int j0 = chunk * CW;

  const int4v*  __restrict__ arow0 = (const int4v*)(adj + (size_t)row0 * GN);
  const int4v*  __restrict__ arow1 = (const int4v*)(adj + (size_t)row1 * GN);
  const float4* __restrict__ fdv   = (const float4*)fd2;

  f32x4 acc0a = {0,0,0,0}, acc1a = {0,0,0,0}, acc2a = {0,0,0,0}, acc3a = {0,0,0,0};
  f32x4 acc0b = {0,0,0,0}, acc1b = {0,0,0,0}, acc2b = {0,0,0,0}, acc3b = {0,0,0,0};
  float ds0 = 0.f, ds1 = 0.f;

  auto pcalc = [&](int a, float fd, float fs, float& dsum) -> float {
    float sv = fs + fd;
    float lv = fmaxf(sv, 0.02f * sv);       // lrelu (commutes with *log2e)
    float pe = __builtin_amdgcn_exp2f(lv);
    pe = (a != 0) ? pe : 0.f;
    dsum += pe;
    return pe;
  };

  auto mk_af = [&](int4v aA, int4v aB, float4 fA, float4 fB,
                   float fs, float& dsum) -> short8 {
    short8 af;
    af[0] = (short)f2bf(pcalc(aA.x, fA.x, fs, dsum));
    af[1] = (short)f2bf(pcalc(aA.y, fA.y, fs, dsum));
    af[2] = (short)f2bf(pcalc(aA.z, fA.z, fs, dsum));
    af[3] = (short)f2bf(pcalc(aA.w, fA.w, fs, dsum));
    af[4] = (short)f2bf(pcalc(aB.x, fB.x, fs, dsum));
    af[5] = (short)f2bf(pcalc(aB.y, fB.y, fs, dsum));
    af[6] = (short)f2bf(pcalc(aB.z, fB.z, fs, dsum));
    af[7] = (short)f2bf(pcalc(aB.w, fB.w, fs, dsum));
    return af;
  };

#pragma unroll 1
  for (int j = j0; j < j0 + CW; j += 64) {
    const int i4 = (j >> 2) + (q << 1);
    // adj: 8 nontemporal 16B loads (2 row groups x 4)
    int4v a00 = __builtin_nontemporal_load(arow0 + i4);
    int4v a01 = __builtin_nontemporal_load(arow0 + i4 + 1);
    int4v a02 = __builtin_nontemporal_load(arow0 + i4 + 8);
    int4v a03 = __builtin_nontemporal_load(arow0 + i4 + 9);
    int4v a10 = __builtin_nontemporal_load(arow1 + i4);
    int4v a11 = __builtin_nontemporal_load(arow1 + i4 + 1);
    int4v a12 = __builtin_nontemporal_load(arow1 + i4 + 8);
    int4v a13 = __builtin_nontemporal_load(arow1 + i4 + 9);
    float4 f0 = fdv[i4];
    float4 f1 = fdv[i4 + 1];
    float4 f2 = fdv[i4 + 8];
    float4 f3 = fdv[i4 + 9];

    // ---- K-step 1 (cols j .. j+31) ----
    {
      short8 af0 = mk_af(a00, a01, f0, f1, fs0, ds0);
      short8 af1 = mk_af(a10, a11, f0, f1, fs1, ds1);
      const unsigned short* wb = whbt + j + q * 8;
      short8 b0 = *(const short8*)(wb + (size_t)(0  + m) * GN);
      short8 b1 = *(const short8*)(wb + (size_t)(16 + m) * GN);
      short8 b2 = *(const short8*)(wb + (size_t)(32 + m) * GN);
      short8 b3 = *(const short8*)(wb + (size_t)(48 + m) * GN);
      acc0a = __builtin_amdgcn_mfma_f32_16x16x32_bf16(af0, b0, acc0a, 0, 0, 0);
      acc1a = __builtin_amdgcn_mfma_f32_16x16x32_bf16(af0, b1, acc1a, 0, 0, 0);
      acc2a = __builtin_amdgcn_mfma_f32_16x16x32_bf16(af0, b2, acc2a, 0, 0, 0);
      acc3a = __builtin_amdgcn_mfma_f32_16x16x32_bf16(af0, b3, acc3a, 0, 0, 0);
      acc0b = __builtin_amdgcn_mfma_f32_16x16x32_bf16(af1, b0, acc0b, 0, 0, 0);
      acc1b = __builtin_amdgcn_mfma_f32_16x16x32_bf16(af1, b1, acc1b, 0, 0, 0);
      acc2b = __builtin_amdgcn_mfma_f32_16x16x32_bf16(af1, b2, acc2b, 0, 0, 0);
      acc3b = __builtin_amdgcn_mfma_f32_16x16x32_bf16(af1, b3, acc3b, 0, 0, 0);
    }
    // ---- K-step 2 (cols j+32 .. j+63) ----
    {
      short8 af0 = mk_af(a02, a03, f2, f3, fs0, ds0);
      short8 af1 = mk_af(a12, a13, f2, f3, fs1, ds1);
      const unsigned short* wb = whbt + (j + 32) + q * 8;
      short8 b0 = *(const short8*)(wb + (size_t)(0  + m) * GN);
      short8 b1 = *(const short8*)(wb + (size_t)(16 + m) * GN);
      short8 b2 = *(const short8*)(wb + (size_t)(32 + m) * GN);
      short8 b3 = *(const short8*)(wb + (size_t)(48 + m) * GN);
      acc0a = __builtin_amdgcn_mfma_f32_16x16x32_bf16(af0, b0, acc0a, 0, 0, 0);
      acc1a = __builtin_amdgcn_mfma_f32_16x16x32_bf16(af0, b1, acc1a, 0, 0, 0);
      acc2a = __builtin_amdgcn_mfma_f32_16x16x32_bf16(af0, b2, acc2a, 0, 0, 0);
      acc3a = __builtin_amdgcn_mfma_f32_16x16x32_bf16(af0, b3, acc3a, 0, 0, 0);
      acc0b = __builtin_amdgcn_mfma_f32_16x16x32_bf16(af1, b0, acc0b, 0, 0, 0);
      acc1b = __builtin_amdgcn_mfma_f32_16x16x32_bf16(af1, b1, acc1b, 0, 0, 0);
      acc2b = __builtin_amdgcn_mfma_f32_16x16x32_bf16(af1, b2, acc2b, 0, 0, 0);
      acc3b = __builtin_amdgcn_mfma_f32_16x16x32_bf16(af1, b3, acc3b, 0, 0, 0);
    }
  }

  // den: lanes m, m+16, m+32, m+48 hold partials of row m (per group)
  ds0 += __shfl_xor(ds0, 16);
  ds0 += __shfl_xor(ds0, 32);
  ds1 += __shfl_xor(ds1, 16);
  ds1 += __shfl_xor(ds1, 32);
  if (q == 0) {
    unsafeAtomicAdd(&den[row0], ds0);
    unsafeAtomicAdd(&den[row1], ds1);
  }

  // C/D layout: D[row = q*4 + r][col = lane&15]
  const int orow0 = strip * 32 + q * 4;
#pragma unroll
  for (int r = 0; r < 4; ++r) {
    float* nra = num + (size_t)(orow0 + r) * GOUT + m;
    unsafeAtomicAdd(nra + 0,  acc0a[r]);
    unsafeAtomicAdd(nra + 16, acc1a[r]);
    unsafeAtomicAdd(nra + 32, acc2a[r]);
    unsafeAtomicAdd(nra + 48, acc3a[r]);
    float* nrb = num + (size_t)(orow0 + 16 + r) * GOUT + m;
    unsafeAtomicAdd(nrb + 0,  acc0b[r]);
    unsafeAtomicAdd(nrb + 16, acc1b[r]);
    unsafeAtomicAdd(nrb + 32, acc2b[r]);
    unsafeAtomicAdd(nrb + 48, acc3b[r]);
  }
}

// ---------------------------------------------------------------------------
// finalize: out = elu(num / den)
// ---------------------------------------------------------------------------
__global__ __launch_bounds__(256) void fin_kernel(
    const float* __restrict__ num, const float* __restrict__ den,
    float* __restrict__ out)
{
  const int g = blockIdx.x * 256 + threadIdx.x;
  if (g < GN * GOUT) {
    float v = num[g] / den[g >> 6];
    out[g] = (v > 0.f) ? v : expm1f(v);
  }
}

extern "C" void kernel_launch(void* const* d_in, const int* in_sizes, int n_in,
                              void* d_out, int out_size, void* d_ws, size_t ws_size,
                              hipStream_t stream) {
  const float* x   = (const float*)d_in[0];
  const int*   adj = (const int*)d_in[1];
  const float* w   = (const float*)d_in[2];
  const float* aw  = (const float*)d_in[3];
  float* out = (float*)d_out;

  // workspace layout (floats): num[N*64] | den[N] | fs2[N] | fd2[N] | whbt(bf16 64*N)
  float* num = (float*)d_ws;
  float* den = num + (size_t)GN * GOUT;
  float* fs2 = den + GN;
  float* fd2 = fs2 + GN;
  unsigned short* whbt = (unsigned short*)(fd2 + GN);

  hipMemsetAsync(num, 0, ((size_t)GN * GOUT + GN) * sizeof(float), stream);
  prep_kernel<<<GN / 64, 256, 0, stream>>>(x, w, aw, whbt, fs2, fd2);
  gat_main<<<(GN / 32) * 8 / 4, 256, 0, stream>>>(adj, whbt, fs2, fd2, num, den);
  fin_kernel<<<(GN * GOUT) / 256, 256, 0, stream>>>(num, den, out);
}